// Round 3
// baseline (2509.710 us; speedup 1.0000x reference)
//
#include <hip/hip_runtime.h>
#include <float.h>

// RVQ inference via MFMA: B=16, C=64, N=4096, Q=8, K=8192, fp32 in/out.
// Round-8 deltas vs round-7 (passed but regressed 1613->2084 us):
//  - Diagnosis: waves_per_eu(4,4) => 128-reg combined budget < ~130-reg live
//    set; allocator kept only 64 arch VGPRs and DEFEATED the A-tile software
//    prefetch (JIT loads). Per-ktile L2 dependency ~200cy on top of ~200cy
//    compute => predicted MfmaUtil ~19%, measured 21.5%. Occupancy rose
//    (43%) but every wave stalls each ktile.
//  - Fix: waves_per_eu(3,3) (~170-reg budget): prefetch fits, 12 waves/CU
//    (vs round-5's 8). MFMA floor 530us, argmax-VALU floor 524us, separate
//    pipes -> target ~1000us.
//  - Add T5 s_setprio(1/0) around the MFMA cluster (waves here are
//    independent, not barrier-lockstep: the regime where setprio pays).
//  - Kept: 2-MFMA distance scheme + top-3 packed argmax + tiered TAU rescore,
//    P=64 (1024 blocks), Bh-only residual frags.
// ws: shalf (QK f32) | WH (QKC bf16-hi u16) | WL (lo) | loss (f32).

typedef float f32x4 __attribute__((ext_vector_type(4)));
typedef short s16x8 __attribute__((ext_vector_type(8)));

constexpr int Bn=16, Cn=64, Nn=4096, Qn=8, Kn=8192;
constexpr int P=64;                     // points per block
constexpr int NPB = Nn/P;               // 64 n-blocks per batch row
constexpr int NBLK = Bn*Nn/P;           // 1024 blocks = 4/CU
constexpr float TAU = 0.15f;            // rescore margin (covers c.rl drop + packing)
constexpr size_t SH_F = (size_t)Qn*Kn;
constexpr size_t W_U  = (size_t)Qn*Kn*Cn;

union U8 { s16x8 v; unsigned short u[8]; };

__device__ __forceinline__ unsigned short bf_rtne(float x){
  unsigned int u = __float_as_uint(x);
  unsigned int r = (u + 0x7fffu + ((u>>16)&1u)) >> 16;
  return (unsigned short)r;
}

__global__ __launch_bounds__(256) void prep_kernel(const float* __restrict__ cb,
    float* __restrict__ shalf, unsigned short* __restrict__ WH,
    unsigned short* __restrict__ WL, float* __restrict__ loss){
  int r = blockIdx.x*256 + threadIdx.x;
  if (r==0) *loss = 0.f;
  const float* row = cb + (size_t)r*Cn;
  float sq = 0.f;
  for (int c=0;c<Cn;++c){
    float v = row[c]; sq = fmaf(v,v,sq);
    unsigned short h = bf_rtne(v);
    float hf = __uint_as_float((unsigned int)h<<16);
    unsigned short l = bf_rtne(v-hf);
    WH[(size_t)r*Cn+c]=h; WL[(size_t)r*Cn+c]=l;
  }
  shalf[r] = -0.5f*sq;
}

__global__ __launch_bounds__(256)
__attribute__((amdgpu_waves_per_eu(3,3)))
void rvq_kernel(
    const float* __restrict__ x, const float* __restrict__ cb,
    const float* __restrict__ shalf,
    const unsigned short* __restrict__ WH, const unsigned short* __restrict__ WL,
    float* __restrict__ out, float* __restrict__ loss_acc){
  __shared__ float4 RES4[P*16];          // res[p][4g..] at [p*16 + (g^(p&15))]
  __shared__ float  red_p1[4][P];        // packed (score|k11) per wave, top-3
  __shared__ float  red_p2[4][P];
  __shared__ float  red_p3[4][P];
  __shared__ int    bk_sh[P];
  __shared__ float  lsum[4];

  const int tid  = threadIdx.x;
  const int wave = tid>>6, lane = tid&63;
  const int quad = lane>>4, l16 = lane&15;
  const int b    = blockIdx.x / NPB;
  const int n0   = (blockIdx.x % NPB)*P;

  { // ---- RES init from x[B,C,N] (coalesced over p) ----
    int p = tid & (P-1), hc = tid>>6;    // 4 chan-groups of 4 float4s each
    const float* xb = x + ((size_t)b*Cn)*Nn + n0 + p;
#pragma unroll
    for (int l=0;l<4;++l){
      int g = hc*4 + l;
      float4 v;
      v.x = xb[(size_t)(4*g+0)*Nn]; v.y = xb[(size_t)(4*g+1)*Nn];
      v.z = xb[(size_t)(4*g+2)*Nn]; v.w = xb[(size_t)(4*g+3)*Nn];
      RES4[p*16 + (g ^ (p&15))] = v;
    }
  }
  __syncthreads();

  float loss_pt = 0.f;

  for (int q=0;q<Qn;++q){
    const unsigned short* WHq = WH + (size_t)q*Kn*Cn;
    const unsigned short* WLq = WL + (size_t)q*Kn*Cn;
    const float* sqq = shalf + (size_t)q*Kn;

    // ---- B-frags (residual, bf16-hi only) in regs: 4 ptiles x 2 Khalves ----
    s16x8 Bh[4][2];
#pragma unroll
    for (int pt=0; pt<4; ++pt){
      int p = pt*16 + l16;
#pragma unroll
      for (int s=0;s<2;++s){
        int g0 = 8*s + quad*2;
        float4 ra = RES4[p*16 + ((g0  ) ^ (p&15))];
        float4 rb = RES4[p*16 + ((g0+1) ^ (p&15))];
        float f[8] = {ra.x,ra.y,ra.z,ra.w, rb.x,rb.y,rb.z,rb.w};
        U8 h;
#pragma unroll
        for (int j=0;j<8;++j) h.u[j]=bf_rtne(f[j]);
        Bh[pt][s]=h.v;
      }
    }

    // ---- scan this wave's 2048-code quarter; packed top-3 per point ----
    float s1[4], s2[4], s3[4];
#pragma unroll
    for (int pt=0;pt<4;++pt){ s1[pt]=-FLT_MAX; s2[pt]=-FLT_MAX; s3[pt]=-FLT_MAX; }

    int kb = wave*2048;
    const int kq = quad*4;
    s16x8 Ah0 = *(const s16x8*)(WHq + (size_t)(kb+l16)*Cn + quad*8);
    s16x8 Ah1 = *(const s16x8*)(WHq + (size_t)(kb+l16)*Cn + 32 + quad*8);
    s16x8 Al0 = *(const s16x8*)(WLq + (size_t)(kb+l16)*Cn + quad*8);
    s16x8 Al1 = *(const s16x8*)(WLq + (size_t)(kb+l16)*Cn + 32 + quad*8);
    f32x4 sv  = *(const f32x4*)(sqq + kb + kq);

    for (int kt=0; kt<128; ++kt){
      int nkb = (kt<127) ? kb+16 : kb;        // prefetch next ktile (L2-hot)
      s16x8 nAh0 = *(const s16x8*)(WHq + (size_t)(nkb+l16)*Cn + quad*8);
      s16x8 nAh1 = *(const s16x8*)(WHq + (size_t)(nkb+l16)*Cn + 32 + quad*8);
      s16x8 nAl0 = *(const s16x8*)(WLq + (size_t)(nkb+l16)*Cn + quad*8);
      s16x8 nAl1 = *(const s16x8*)(WLq + (size_t)(nkb+l16)*Cn + 32 + quad*8);
      f32x4 nsv  = *(const f32x4*)(sqq + nkb + kq);

      const unsigned int kloc = (unsigned int)((kb & 2047) | kq); // 11-bit local

#pragma unroll
      for (int pp=0; pp<2; ++pp){
        const int p0 = 2*pp, p1 = 2*pp+1;
        f32x4 a0, a1;                          // C-init = -0.5|c|^2 via sv
        __builtin_amdgcn_s_setprio(1);
        a0 = __builtin_amdgcn_mfma_f32_16x16x32_bf16(Ah0, Bh[p0][0], sv, 0,0,0);
        a1 = __builtin_amdgcn_mfma_f32_16x16x32_bf16(Ah0, Bh[p1][0], sv, 0,0,0);
        a0 = __builtin_amdgcn_mfma_f32_16x16x32_bf16(Al0, Bh[p0][0], a0, 0,0,0);
        a1 = __builtin_amdgcn_mfma_f32_16x16x32_bf16(Al0, Bh[p1][0], a1, 0,0,0);
        a0 = __builtin_amdgcn_mfma_f32_16x16x32_bf16(Ah1, Bh[p0][1], a0, 0,0,0);
        a1 = __builtin_amdgcn_mfma_f32_16x16x32_bf16(Ah1, Bh[p1][1], a1, 0,0,0);
        a0 = __builtin_amdgcn_mfma_f32_16x16x32_bf16(Al1, Bh[p0][1], a0, 0,0,0);
        a1 = __builtin_amdgcn_mfma_f32_16x16x32_bf16(Al1, Bh[p1][1], a1, 0,0,0);
        __builtin_amdgcn_s_setprio(0);
#pragma unroll
        for (int r=0;r<4;++r){
          // pack index into low 11 mantissa bits; top-3 via fmax + 2x fmed3
          float pv0 = __uint_as_float((__float_as_uint(a0[r]) & 0xFFFFF800u)
                                      | (kloc + (unsigned)r));
          float pv1 = __uint_as_float((__float_as_uint(a1[r]) & 0xFFFFF800u)
                                      | (kloc + (unsigned)r));
          float n20 = __builtin_amdgcn_fmed3f(pv0, s1[p0], s2[p0]);
          float n30 = __builtin_amdgcn_fmed3f(pv0, s2[p0], s3[p0]);
          s1[p0] = fmaxf(s1[p0], pv0); s2[p0] = n20; s3[p0] = n30;
          float n21 = __builtin_amdgcn_fmed3f(pv1, s1[p1], s2[p1]);
          float n31 = __builtin_amdgcn_fmed3f(pv1, s2[p1], s3[p1]);
          s1[p1] = fmaxf(s1[p1], pv1); s2[p1] = n21; s3[p1] = n31;
        }
      }
      kb = nkb; Ah0=nAh0; Ah1=nAh1; Al0=nAl0; Al1=nAl1; sv=nsv;
    }

    // ---- cross-quad top-3 merge in packed domain (k travels in the bits) ----
#pragma unroll
    for (int pt=0;pt<4;++pt){
#pragma unroll
      for (int m=16; m<=32; m<<=1){
        float o1 = __shfl_xor(s1[pt], m, 64);
        float o2 = __shfl_xor(s2[pt], m, 64);
        float o3 = __shfl_xor(s3[pt], m, 64);
        // merge two sorted triples: top-3 of union (branchless identity)
        float A  = fminf(s1[pt], o1);
        float n1 = fmaxf(s1[pt], o1);
        float Bv = fmaxf(s2[pt], o2);
        float D  = fmaxf(s3[pt], o3);
        float n2 = fmaxf(A, Bv);
        float n3 = fmaxf(fminf(A, Bv), D);
        s1[pt]=n1; s2[pt]=n2; s3[pt]=n3;
      }
      if (quad==0){
        int p = pt*16 + l16;
        red_p1[wave][p]=s1[pt]; red_p2[wave][p]=s2[pt]; red_p3[wave][p]=s3[pt];
      }
    }
    __syncthreads();

    // ---- per-point 4-wave top-3 merge (track wave origin) + tiered rescore ----
    if (tid < P){
      float S1 = red_p1[0][tid]; int W1 = 0;
      float S2 = red_p2[0][tid]; int W2 = 0;
      float S3 = red_p3[0][tid]; int W3 = 0;
#pragma unroll
      for (int w=1; w<4; ++w){
        float o1 = red_p1[w][tid], o2 = red_p2[w][tid], o3 = red_p3[w][tid];
        if (o1 > S1){ S3=S2;W3=W2; S2=S1;W2=W1; S1=o1;W1=w; }
        else if (o1 > S2){ S3=S2;W3=W2; S2=o1;W2=w; }
        else if (o1 > S3){ S3=o1;W3=w; }
        if (o2 > S2){ S3=S2;W3=W2; S2=o2;W2=w; }
        else if (o2 > S3){ S3=o2;W3=w; }
        if (o3 > S3){ S3=o3;W3=w; }
      }
      int K1 = (W1<<11) | (int)(__float_as_uint(S1) & 2047u);
      if (S1 - S2 < TAU){   // near-tie: exact fp32 rescore of top-2
        int K2 = (W2<<11) | (int)(__float_as_uint(S2) & 2047u);
        float d1 = sqq[K1], d2 = sqq[K2];
        const float4* r1 = (const float4*)(cb + ((size_t)q*Kn + K1)*Cn);
        const float4* r2 = (const float4*)(cb + ((size_t)q*Kn + K2)*Cn);
#pragma unroll
        for (int g=0; g<16; ++g){
          float4 rv = RES4[tid*16 + (g ^ (tid&15))];
          float4 c1 = r1[g], c2 = r2[g];
          d1=fmaf(rv.x,c1.x,d1); d1=fmaf(rv.y,c1.y,d1);
          d1=fmaf(rv.z,c1.z,d1); d1=fmaf(rv.w,c1.w,d1);
          d2=fmaf(rv.x,c2.x,d2); d2=fmaf(rv.y,c2.y,d2);
          d2=fmaf(rv.z,c2.z,d2); d2=fmaf(rv.w,c2.w,d2);
        }
        if ( (d2 > d1) || (d2==d1 && K2<K1) ){ K1 = K2; d1 = d2; }
        if (S1 - S3 < TAU){ // rare (~0.2%): 3rd candidate also in the noise band
          int K3 = (W3<<11) | (int)(__float_as_uint(S3) & 2047u);
          float d3 = sqq[K3];
          const float4* r3 = (const float4*)(cb + ((size_t)q*Kn + K3)*Cn);
#pragma unroll
          for (int g=0; g<16; ++g){
            float4 rv = RES4[tid*16 + (g ^ (tid&15))];
            float4 c3 = r3[g];
            d3=fmaf(rv.x,c3.x,d3); d3=fmaf(rv.y,c3.y,d3);
            d3=fmaf(rv.z,c3.z,d3); d3=fmaf(rv.w,c3.w,d3);
          }
          if ( (d3 > d1) || (d3==d1 && K3<K1) ) K1 = K3;
        }
      }
      bk_sh[tid]=K1;
      out[(size_t)(Bn*Cn*Nn) + (size_t)(b*Nn + n0 + tid)*Qn + q] = (float)K1;
    }
    __syncthreads();

    // ---- residual update (exact fp32, winner row L2-hot) + loss ----
    {
      int p = tid & (P-1), hc = tid>>6;
      int bk = bk_sh[p];
      const float4* crow = (const float4*)(cb + ((size_t)q*Kn + bk)*Cn) + hc*4;
#pragma unroll
      for (int l=0;l<4;++l){
        int g = hc*4 + l;
        float4 v = crow[l];
        int idx = p*16 + (g ^ (p&15));
        float4 rv = RES4[idx];
        rv.x-=v.x; rv.y-=v.y; rv.z-=v.z; rv.w-=v.w;
        RES4[idx]=rv;
        loss_pt = fmaf(rv.x,rv.x,loss_pt); loss_pt = fmaf(rv.y,rv.y,loss_pt);
        loss_pt = fmaf(rv.z,rv.z,loss_pt); loss_pt = fmaf(rv.w,rv.w,loss_pt);
      }
    }
    __syncthreads();
  } // q

  // ---- quantized = x - final residual (coalesced over p) ----
  {
    int p = tid & (P-1), hc = tid>>6;
    const float* xb = x + ((size_t)b*Cn)*Nn + n0 + p;
    float*       ob = out + ((size_t)b*Cn)*Nn + n0 + p;
#pragma unroll
    for (int l=0;l<4;++l){
      int g = hc*4+l, c = 4*g;
      float4 rv = RES4[p*16 + (g ^ (p&15))];
      ob[(size_t)(c+0)*Nn] = xb[(size_t)(c+0)*Nn] - rv.x;
      ob[(size_t)(c+1)*Nn] = xb[(size_t)(c+1)*Nn] - rv.y;
      ob[(size_t)(c+2)*Nn] = xb[(size_t)(c+2)*Nn] - rv.z;
      ob[(size_t)(c+3)*Nn] = xb[(size_t)(c+3)*Nn] - rv.w;
    }
  }
  float s = loss_pt;
#pragma unroll
  for (int off=32; off>0; off>>=1) s += __shfl_down(s, off, 64);
  if (lane==0) lsum[wave]=s;
  __syncthreads();
  if (tid==0) atomicAdd(loss_acc, lsum[0]+lsum[1]+lsum[2]+lsum[3]);
}

__global__ void final_kernel(const float* __restrict__ loss_acc,
                             float* __restrict__ out){
  out[(size_t)Bn*Cn*Nn + (size_t)Bn*Nn*Qn] =
      loss_acc[0] * (1.0f / ((float)Qn * Bn * Nn * Cn));
}

extern "C" void kernel_launch(void* const* d_in, const int* in_sizes, int n_in,
                              void* d_out, int out_size, void* d_ws, size_t ws_size,
                              hipStream_t stream) {
  const float* x  = (const float*)d_in[0];
  const float* cb = (const float*)d_in[1];
  float* out = (float*)d_out;
  float* ws  = (float*)d_ws;

  float* shalf = ws;
  unsigned short* WH = (unsigned short*)(ws + SH_F);
  unsigned short* WL = WH + W_U;
  float* loss = (float*)(WL + W_U);

  hipLaunchKernelGGL(prep_kernel, dim3((Qn*Kn)/256), dim3(256), 0, stream,
                     cb, shalf, WH, WL, loss);
  hipLaunchKernelGGL(rvq_kernel, dim3(NBLK), dim3(256), 0, stream,
                     x, cb, shalf, WH, WL, out, loss);
  hipLaunchKernelGGL(final_kernel, dim3(1), dim3(1), 0, stream, loss, out);
}

// Round 5
// 1439.926 us; speedup vs baseline: 1.7429x; 1.7429x over previous
//
#include <hip/hip_runtime.h>
#include <float.h>

// RVQ inference via MFMA: B=16, C=64, N=4096, Q=8, K=8192, fp32 in/out.
// Round-10: K-partitioned scan (R7-proven logic) + wave-private LDS staging.
//  - R9 audit: (a) global_load_lds was given a per-lane LDS pointer (must be
//    wave-uniform base; HW adds lane*size) -- fixed; (b) point-partitioned
//    tiles make all 4 waves read the same LDS tile: 655us of ds_read_b128
//    port per CU > 530us MFMA floor -- structural dead end.
//  - This structure: each wave scans its private 2048-code quarter (exactly
//    R7's proven top-3/packing/merge/rescore logic). A-tiles (16 codes,
//    WH 2KB + WL 2KB) staged into WAVE-PRIVATE LDS double-buffers via
//    global_load_lds(16B); sync = one s_waitcnt vmcnt(0) per ktile, NO
//    barriers in the K-loop. 8 B-ptiles/wave -> 32 MFMA per 4 ds_read_b128.
//  - XOR-swizzle byte^=((row&7)<<4) BOTH sides (rule 21): pre-swizzled
//    global source in stage16 + swizzled ds_read -> balanced banks.
//  - Floors: VALU ~256us, LDS ~245us, L2 ~230us, MFMA ~132us.
// ws: shalf (QK f32) | WH (QKC bf16-hi u16) | WL (lo) | loss (f32).

typedef float f32x4 __attribute__((ext_vector_type(4)));
typedef short s16x8 __attribute__((ext_vector_type(8)));

constexpr int Bn=16, Cn=64, Nn=4096, Qn=8, Kn=8192;
constexpr int P=128;                    // points per block
constexpr int NPB = Nn/P;               // 32 n-blocks per batch row
constexpr int NBLK = Bn*Nn/P;           // 512 blocks = 2/CU
constexpr float TAU = 0.15f;            // rescore margin (c.rl drop + packing)
constexpr size_t SH_F = (size_t)Qn*Kn;
constexpr size_t W_U  = (size_t)Qn*Kn*Cn;

union U8 { s16x8 v; unsigned short u[8]; };

__device__ __forceinline__ unsigned short bf_rtne(float x){
  unsigned int u = __float_as_uint(x);
  unsigned int r = (u + 0x7fffu + ((u>>16)&1u)) >> 16;
  return (unsigned short)r;
}

__device__ __forceinline__ void gl16(const void* g, void* l){
  __builtin_amdgcn_global_load_lds(
      (const __attribute__((address_space(1))) unsigned int*)g,
      (      __attribute__((address_space(3))) unsigned int*)l, 16, 0, 0);
}

// Stage 16 codebook rows (16 x 128B = 2KB) into a wave-private LDS chunk.
// LDS dest is LINEAR (wave-uniform base + lane*16, hardware lane placement);
// the global SOURCE column is pre-swizzled by the same involution the reader
// applies: col' = col ^ ((row&7)<<4).  Two calls cover rows 0..7 / 8..15.
__device__ __forceinline__ void stage16(const unsigned short* Wq, int kb,
                                        char* lds /*wave-uniform*/, int lane){
  int rl   = lane>>3;                    // row & 7
  int scol = ((lane&7) ^ rl) << 4;       // swizzled source column (bytes)
  const char* g0 = (const char*)Wq + (size_t)(kb + rl)*128 + (size_t)scol;
  gl16(g0,         lds);                 // rows 0..7  -> LDS [0,1024)
  gl16(g0 + 8*128, lds + 1024);          // rows 8..15 -> LDS [1024,2048)
}

__global__ __launch_bounds__(256) void prep_kernel(const float* __restrict__ cb,
    float* __restrict__ shalf, unsigned short* __restrict__ WH,
    unsigned short* __restrict__ WL, float* __restrict__ loss){
  int r = blockIdx.x*256 + threadIdx.x;
  if (r==0) *loss = 0.f;
  const float* row = cb + (size_t)r*Cn;
  float sq = 0.f;
  for (int c=0;c<Cn;++c){
    float v = row[c]; sq = fmaf(v,v,sq);
    unsigned short h = bf_rtne(v);
    float hf = __uint_as_float((unsigned int)h<<16);
    unsigned short l = bf_rtne(v-hf);
    WH[(size_t)r*Cn+c]=h; WL[(size_t)r*Cn+c]=l;
  }
  shalf[r] = -0.5f*sq;
}

__global__ __launch_bounds__(256)
__attribute__((amdgpu_waves_per_eu(2,2)))
void rvq_kernel(
    const float* __restrict__ x, const float* __restrict__ cb,
    const float* __restrict__ shalf,
    const unsigned short* __restrict__ WH, const unsigned short* __restrict__ WL,
    float* __restrict__ out, float* __restrict__ loss_acc){
  __shared__ float4 RES4[P*16];              // 32KB: res[p][g^(p&15)]
  __shared__ __align__(16) char ABUF[4][2][2][2048]; // wave x dbuf x {WH,WL}
  __shared__ float  red_p1[4][P];            // packed (score|k11) per wave
  __shared__ float  red_p2[4][P];
  __shared__ float  red_p3[4][P];
  __shared__ int    bk_sh[P];
  __shared__ float  lsum[4];

  const int tid  = threadIdx.x;
  const int wave = tid>>6, lane = tid&63;
  const int quad = lane>>4, l16 = lane&15;
  const int b    = blockIdx.x / NPB;
  const int n0   = (blockIdx.x % NPB)*P;

  { // ---- RES init from x[B,C,N] (coalesced over p) ----
    int p = tid & (P-1), hc = tid>>7;
    const float* xb = x + ((size_t)b*Cn)*Nn + n0 + p;
#pragma unroll
    for (int l=0;l<8;++l){
      int g = hc*8 + l;
      float4 v;
      v.x = xb[(size_t)(4*g+0)*Nn]; v.y = xb[(size_t)(4*g+1)*Nn];
      v.z = xb[(size_t)(4*g+2)*Nn]; v.w = xb[(size_t)(4*g+3)*Nn];
      RES4[p*16 + (g ^ (p&15))] = v;
    }
  }
  // prologue: stage q=0 first ktile into this wave's buffer 0
  stage16(WH, wave*2048, &ABUF[wave][0][0][0], lane);
  stage16(WL, wave*2048, &ABUF[wave][0][1][0], lane);
  __syncthreads();   // drains vmcnt too

  float loss_pt = 0.f;
  int cur = 0;

  for (int q=0;q<Qn;++q){
    const unsigned short* WHq = WH + (size_t)q*Kn*Cn;
    const unsigned short* WLq = WL + (size_t)q*Kn*Cn;
    const float* sqq = shalf + (size_t)q*Kn;

    // ---- B-frags (all 8 ptiles, bf16-hi residual) in regs: 64 VGPR ----
    s16x8 Bh[8][2];
#pragma unroll
    for (int pt=0; pt<8; ++pt){
      int p = pt*16 + l16;
#pragma unroll
      for (int s=0;s<2;++s){
        int g0 = 8*s + quad*2;
        float4 ra = RES4[p*16 + ((g0  ) ^ (p&15))];
        float4 rb = RES4[p*16 + ((g0+1) ^ (p&15))];
        float f[8] = {ra.x,ra.y,ra.z,ra.w, rb.x,rb.y,rb.z,rb.w};
        U8 h;
#pragma unroll
        for (int j=0;j<8;++j) h.u[j]=bf_rtne(f[j]);
        Bh[pt][s]=h.v;
      }
    }

    // ---- scan this wave's 2048-code quarter; packed top-3 per point ----
    float s1[8], s2[8], s3[8];
#pragma unroll
    for (int pt=0;pt<8;++pt){ s1[pt]=-FLT_MAX; s2[pt]=-FLT_MAX; s3[pt]=-FLT_MAX; }

    int kb = wave*2048;
    const int sw = (l16&7)<<4;

    for (int kt=0; kt<128; ++kt){
      { // stage next ktile (or next-q ktile 0) into the other buffer
        char* nb0 = &ABUF[wave][cur^1][0][0];
        char* nb1 = &ABUF[wave][cur^1][1][0];
        if (kt < 127){
          stage16(WHq, kb+16, nb0, lane);
          stage16(WLq, kb+16, nb1, lane);
        } else if (q < Qn-1){
          stage16(WHq + (size_t)Kn*Cn, wave*2048, nb0, lane);
          stage16(WLq + (size_t)Kn*Cn, wave*2048, nb1, lane);
        }
      }
      const char* tw = &ABUF[wave][cur][0][0];
      const char* tl = &ABUF[wave][cur][1][0];
      s16x8 Ah0 = *(const s16x8*)(tw + l16*128 + (( 0 + quad*16) ^ sw));
      s16x8 Ah1 = *(const s16x8*)(tw + l16*128 + ((64 + quad*16) ^ sw));
      s16x8 Al0 = *(const s16x8*)(tl + l16*128 + (( 0 + quad*16) ^ sw));
      s16x8 Al1 = *(const s16x8*)(tl + l16*128 + ((64 + quad*16) ^ sw));
      f32x4 sv  = *(const f32x4*)(sqq + kb + quad*4);
      const unsigned int kloc = (unsigned int)((kb & 2047) | (quad*4));

#pragma unroll
      for (int pp=0; pp<4; ++pp){
        const int p0 = 2*pp, p1 = 2*pp+1;
        f32x4 a0, a1;                          // C-init = -0.5|c|^2 via sv
        a0 = __builtin_amdgcn_mfma_f32_16x16x32_bf16(Ah0, Bh[p0][0], sv, 0,0,0);
        a1 = __builtin_amdgcn_mfma_f32_16x16x32_bf16(Ah0, Bh[p1][0], sv, 0,0,0);
        a0 = __builtin_amdgcn_mfma_f32_16x16x32_bf16(Al0, Bh[p0][0], a0, 0,0,0);
        a1 = __builtin_amdgcn_mfma_f32_16x16x32_bf16(Al0, Bh[p1][0], a1, 0,0,0);
        a0 = __builtin_amdgcn_mfma_f32_16x16x32_bf16(Ah1, Bh[p0][1], a0, 0,0,0);
        a1 = __builtin_amdgcn_mfma_f32_16x16x32_bf16(Ah1, Bh[p1][1], a1, 0,0,0);
        a0 = __builtin_amdgcn_mfma_f32_16x16x32_bf16(Al1, Bh[p0][1], a0, 0,0,0);
        a1 = __builtin_amdgcn_mfma_f32_16x16x32_bf16(Al1, Bh[p1][1], a1, 0,0,0);
#pragma unroll
        for (int r=0;r<4;++r){
          // pack index into low 11 mantissa bits; top-3 via fmax + 2x fmed3
          float pv0 = __uint_as_float((__float_as_uint(a0[r]) & 0xFFFFF800u)
                                      | (kloc + (unsigned)r));
          float pv1 = __uint_as_float((__float_as_uint(a1[r]) & 0xFFFFF800u)
                                      | (kloc + (unsigned)r));
          float n20 = __builtin_amdgcn_fmed3f(pv0, s1[p0], s2[p0]);
          float n30 = __builtin_amdgcn_fmed3f(pv0, s2[p0], s3[p0]);
          s1[p0] = fmaxf(s1[p0], pv0); s2[p0] = n20; s3[p0] = n30;
          float n21 = __builtin_amdgcn_fmed3f(pv1, s1[p1], s2[p1]);
          float n31 = __builtin_amdgcn_fmed3f(pv1, s2[p1], s3[p1]);
          s1[p1] = fmaxf(s1[p1], pv1); s2[p1] = n21; s3[p1] = n31;
        }
      }
      // drain this ktile's staging DMA before the next iteration reads it
      asm volatile("s_waitcnt vmcnt(0)" ::: "memory");
      __builtin_amdgcn_sched_barrier(0);
      cur ^= 1; kb += 16;
    }

    // ---- cross-quad top-3 merge in packed domain (k travels in the bits) ----
#pragma unroll
    for (int pt=0;pt<8;++pt){
#pragma unroll
      for (int m=16; m<=32; m<<=1){
        float o1 = __shfl_xor(s1[pt], m, 64);
        float o2 = __shfl_xor(s2[pt], m, 64);
        float o3 = __shfl_xor(s3[pt], m, 64);
        float A  = fminf(s1[pt], o1);
        float n1 = fmaxf(s1[pt], o1);
        float Bv = fmaxf(s2[pt], o2);
        float D  = fmaxf(s3[pt], o3);
        float n2 = fmaxf(A, Bv);
        float n3 = fmaxf(fminf(A, Bv), D);
        s1[pt]=n1; s2[pt]=n2; s3[pt]=n3;
      }
      if (quad==0){
        int p = pt*16 + l16;
        red_p1[wave][p]=s1[pt]; red_p2[wave][p]=s2[pt]; red_p3[wave][p]=s3[pt];
      }
    }
    __syncthreads();

    // ---- per-point 4-wave top-3 merge (track wave origin) + tiered rescore ----
    if (tid < P){
      float S1 = red_p1[0][tid]; int W1 = 0;
      float S2 = red_p2[0][tid]; int W2 = 0;
      float S3 = red_p3[0][tid]; int W3 = 0;
#pragma unroll
      for (int w=1; w<4; ++w){
        float o1 = red_p1[w][tid], o2 = red_p2[w][tid], o3 = red_p3[w][tid];
        if (o1 > S1){ S3=S2;W3=W2; S2=S1;W2=W1; S1=o1;W1=w; }
        else if (o1 > S2){ S3=S2;W3=W2; S2=o1;W2=w; }
        else if (o1 > S3){ S3=o1;W3=w; }
        if (o2 > S2){ S3=S2;W3=W2; S2=o2;W2=w; }
        else if (o2 > S3){ S3=o2;W3=w; }
        if (o3 > S3){ S3=o3;W3=w; }
      }
      int K1 = (W1<<11) | (int)(__float_as_uint(S1) & 2047u);
      if (S1 - S2 < TAU){   // near-tie: exact fp32 rescore of top-2
        int K2 = (W2<<11) | (int)(__float_as_uint(S2) & 2047u);
        float d1 = sqq[K1], d2 = sqq[K2];
        const float4* r1 = (const float4*)(cb + ((size_t)q*Kn + K1)*Cn);
        const float4* r2 = (const float4*)(cb + ((size_t)q*Kn + K2)*Cn);
#pragma unroll
        for (int g=0; g<16; ++g){
          float4 rv = RES4[tid*16 + (g ^ (tid&15))];
          float4 c1 = r1[g], c2 = r2[g];
          d1=fmaf(rv.x,c1.x,d1); d1=fmaf(rv.y,c1.y,d1);
          d1=fmaf(rv.z,c1.z,d1); d1=fmaf(rv.w,c1.w,d1);
          d2=fmaf(rv.x,c2.x,d2); d2=fmaf(rv.y,c2.y,d2);
          d2=fmaf(rv.z,c2.z,d2); d2=fmaf(rv.w,c2.w,d2);
        }
        if ( (d2 > d1) || (d2==d1 && K2<K1) ){ K1 = K2; d1 = d2; }
        if (S1 - S3 < TAU){ // rare: 3rd candidate also inside the noise band
          int K3 = (W3<<11) | (int)(__float_as_uint(S3) & 2047u);
          float d3 = sqq[K3];
          const float4* r3 = (const float4*)(cb + ((size_t)q*Kn + K3)*Cn);
#pragma unroll
          for (int g=0; g<16; ++g){
            float4 rv = RES4[tid*16 + (g ^ (tid&15))];
            float4 c3 = r3[g];
            d3=fmaf(rv.x,c3.x,d3); d3=fmaf(rv.y,c3.y,d3);
            d3=fmaf(rv.z,c3.z,d3); d3=fmaf(rv.w,c3.w,d3);
          }
          if ( (d3 > d1) || (d3==d1 && K3<K1) ) K1 = K3;
        }
      }
      bk_sh[tid]=K1;
      out[(size_t)(Bn*Cn*Nn) + (size_t)(b*Nn + n0 + tid)*Qn + q] = (float)K1;
    }
    __syncthreads();

    // ---- residual update (exact fp32, winner row L2-hot) + loss ----
    {
      int p = tid & (P-1), hc = tid>>7;
      int bk = bk_sh[p];
      const float4* crow = (const float4*)(cb + ((size_t)q*Kn + bk)*Cn) + hc*8;
#pragma unroll
      for (int l=0;l<8;++l){
        int g = hc*8 + l;
        float4 v = crow[l];
        int idx = p*16 + (g ^ (p&15));
        float4 rv = RES4[idx];
        rv.x-=v.x; rv.y-=v.y; rv.z-=v.z; rv.w-=v.w;
        RES4[idx]=rv;
        loss_pt = fmaf(rv.x,rv.x,loss_pt); loss_pt = fmaf(rv.y,rv.y,loss_pt);
        loss_pt = fmaf(rv.z,rv.z,loss_pt); loss_pt = fmaf(rv.w,rv.w,loss_pt);
      }
    }
    __syncthreads();
  } // q

  // ---- quantized = x - final residual (coalesced over p) ----
  {
    int p = tid & (P-1), hc = tid>>7;
    const float* xb = x + ((size_t)b*Cn)*Nn + n0 + p;
    float*       ob = out + ((size_t)b*Cn)*Nn + n0 + p;
#pragma unroll
    for (int l=0;l<8;++l){
      int g = hc*8+l, c = 4*g;
      float4 rv = RES4[p*16 + (g ^ (p&15))];
      ob[(size_t)(c+0)*Nn] = xb[(size_t)(c+0)*Nn] - rv.x;
      ob[(size_t)(c+1)*Nn] = xb[(size_t)(c+1)*Nn] - rv.y;
      ob[(size_t)(c+2)*Nn] = xb[(size_t)(c+2)*Nn] - rv.z;
      ob[(size_t)(c+3)*Nn] = xb[(size_t)(c+3)*Nn] - rv.w;
    }
  }
  float s = loss_pt;
#pragma unroll
  for (int off=32; off>0; off>>=1) s += __shfl_down(s, off, 64);
  if (lane==0) lsum[wave]=s;
  __syncthreads();
  if (tid==0) atomicAdd(loss_acc, lsum[0]+lsum[1]+lsum[2]+lsum[3]);
}

__global__ void final_kernel(const float* __restrict__ loss_acc,
                             float* __restrict__ out){
  out[(size_t)Bn*Cn*Nn + (size_t)Bn*Nn*Qn] =
      loss_acc[0] * (1.0f / ((float)Qn * Bn * Nn * Cn));
}

extern "C" void kernel_launch(void* const* d_in, const int* in_sizes, int n_in,
                              void* d_out, int out_size, void* d_ws, size_t ws_size,
                              hipStream_t stream) {
  const float* x  = (const float*)d_in[0];
  const float* cb = (const float*)d_in[1];
  float* out = (float*)d_out;
  float* ws  = (float*)d_ws;

  float* shalf = ws;
  unsigned short* WH = (unsigned short*)(ws + SH_F);
  unsigned short* WL = WH + W_U;
  float* loss = (float*)(WL + W_U);

  hipLaunchKernelGGL(prep_kernel, dim3((Qn*Kn)/256), dim3(256), 0, stream,
                     cb, shalf, WH, WL, loss);
  hipLaunchKernelGGL(rvq_kernel, dim3(NBLK), dim3(256), 0, stream,
                     x, cb, shalf, WH, WL, out, loss);
  hipLaunchKernelGGL(final_kernel, dim3(1), dim3(1), 0, stream, loss, out);
}